// Round 1
// baseline (144.073 us; speedup 1.0000x reference)
//
#include <hip/hip_runtime.h>

#define N_    4
#define CIN   64
#define COUT  64
#define H_    128
#define W_    128
#define HO_   128
#define WO_   128
#define K2_   9

// One-shot weight transpose: w[co][ci][k] -> wt[k][ci][co] so the main
// kernel's per-tap W staging is a coalesced float4 stream.
__global__ void DeformConv2d_wtrans(const float* __restrict__ w,
                                    float* __restrict__ wt) {
    int i = blockIdx.x * 256 + threadIdx.x;           // over 36864
    if (i < COUT * CIN * K2_) {
        int k  = i % K2_;
        int ci = (i / K2_) % CIN;
        int co = i / (K2_ * CIN);
        wt[(k * CIN + ci) * COUT + co] = w[i];
    }
}

template <bool USE_WS>
__global__ __launch_bounds__(256, 4) void DeformConv2d_kernel(
    const float* __restrict__ x,       // [N,CIN,H,W]
    const float* __restrict__ offset,  // [N,2*K2,HO,WO]
    const float* __restrict__ mask,    // [N,K2,HO,WO]
    const float* __restrict__ weight,  // [COUT,CIN,KH,KW]
    const float* __restrict__ wt,      // [K2,CIN,COUT] (if USE_WS)
    float* __restrict__ out)           // [N,COUT,HO,WO]
{
    __shared__ float W_lds[CIN * COUT];   // [ci][co]
    __shared__ float S_lds[CIN * 64];     // [ci][px]
    __shared__ float cfy[64], cfx[64], cm[64];
    __shared__ int   cy0[64], cx0[64];

    const int tid = threadIdx.x;
    const int blk = blockIdx.x;            // 0..1023
    const int wb  = (blk & 1) * 64;        // wo base
    const int ho  = (blk >> 1) & 127;
    const int n   = blk >> 8;              // 0..3

    const int tr = tid >> 4;               // 0..15 -> co group (co = tr*4+j)
    const int tc = tid & 15;               // 0..15 -> px group (px = tc*4+i)

    float acc[4][4];
#pragma unroll
    for (int j = 0; j < 4; ++j)
#pragma unroll
        for (int i = 0; i < 4; ++i) acc[j][i] = 0.f;

    for (int k = 0; k < K2_; ++k) {
        __syncthreads();   // previous tap's GEMM done reading LDS

        // ---- phase 1: per-pixel bilinear coords + W_k staging ----
        if (tid < 64) {
            const int wo = wb + tid;
            const int ki = k / 3, kj = k % 3;
            const float dy = offset[((n * (2 * K2_) + 2 * k)     * HO_ + ho) * WO_ + wo];
            const float dx = offset[((n * (2 * K2_) + 2 * k + 1) * HO_ + ho) * WO_ + wo];
            const float m  = mask  [((n * K2_       + k)         * HO_ + ho) * WO_ + wo];
            const float yy = (float)(ho - 1 + ki) + dy;
            const float xx = (float)(wo - 1 + kj) + dx;
            const float y0f = floorf(yy), x0f = floorf(xx);
            cy0[tid] = (int)y0f;
            cx0[tid] = (int)x0f;
            cfy[tid] = yy - y0f;
            cfx[tid] = xx - x0f;
            cm[tid]  = m;
        }
        if (USE_WS) {
            const float4* wk = (const float4*)(wt + k * CIN * COUT);
#pragma unroll
            for (int e = 0; e < 4; ++e) {           // 1024 float4 / 256 thr
                int i4 = e * 256 + tid;
                ((float4*)W_lds)[i4] = wk[i4];
            }
        } else {
#pragma unroll
            for (int e = 0; e < 16; ++e) {
                int i  = e * 256 + tid;
                int ci = i >> 6, co = i & 63;
                W_lds[ci * 64 + co] = weight[(co * CIN + ci) * K2_ + k];
            }
        }
        __syncthreads();

        // ---- phase 2: sample S_k[ci][px] = bilinear(x)*mask ----
#pragma unroll
        for (int e = 0; e < 16; ++e) {
            int i  = e * 256 + tid;
            int ci = i >> 6, px = i & 63;
            int   y0 = cy0[px], x0 = cx0[px];
            float fy = cfy[px], fx = cfx[px], m = cm[px];
            const float* xc = x + (size_t)(n * CIN + ci) * (H_ * W_);
            bool yv0 = (y0 >= 0)  && (y0 < H_);
            bool yv1 = (y0 >= -1) && (y0 < H_ - 1);
            bool xv0 = (x0 >= 0)  && (x0 < W_);
            bool xv1 = (x0 >= -1) && (x0 < W_ - 1);
            float v00 = (yv0 && xv0) ? xc[y0 * W_ + x0]           : 0.f;
            float v01 = (yv0 && xv1) ? xc[y0 * W_ + x0 + 1]       : 0.f;
            float v10 = (yv1 && xv0) ? xc[(y0 + 1) * W_ + x0]     : 0.f;
            float v11 = (yv1 && xv1) ? xc[(y0 + 1) * W_ + x0 + 1] : 0.f;
            float v = (v00 * (1.f - fy) + v10 * fy) * (1.f - fx)
                    + (v01 * (1.f - fy) + v11 * fy) * fx;
            S_lds[ci * 64 + px] = v * m;
        }
        __syncthreads();

        // ---- phase 3: 64x64x64 mini-GEMM, 4x4 per thread ----
#pragma unroll 8
        for (int ci = 0; ci < CIN; ++ci) {
            const float4 a = *(const float4*)&W_lds[ci * 64 + tr * 4];
            const float4 b = *(const float4*)&S_lds[ci * 64 + tc * 4];
            acc[0][0] += a.x * b.x; acc[0][1] += a.x * b.y;
            acc[0][2] += a.x * b.z; acc[0][3] += a.x * b.w;
            acc[1][0] += a.y * b.x; acc[1][1] += a.y * b.y;
            acc[1][2] += a.y * b.z; acc[1][3] += a.y * b.w;
            acc[2][0] += a.z * b.x; acc[2][1] += a.z * b.y;
            acc[2][2] += a.z * b.z; acc[2][3] += a.z * b.w;
            acc[3][0] += a.w * b.x; acc[3][1] += a.w * b.y;
            acc[3][2] += a.w * b.z; acc[3][3] += a.w * b.w;
        }
    }

    // ---- epilogue: coalesced float4 stores ----
    const int co0 = tr * 4;
    const int wo0 = wb + tc * 4;
#pragma unroll
    for (int j = 0; j < 4; ++j) {
        float4 v;
        v.x = acc[j][0]; v.y = acc[j][1]; v.z = acc[j][2]; v.w = acc[j][3];
        *(float4*)&out[((size_t)(n * COUT + co0 + j) * HO_ + ho) * WO_ + wo0] = v;
    }
}

extern "C" void kernel_launch(void* const* d_in, const int* in_sizes, int n_in,
                              void* d_out, int out_size, void* d_ws, size_t ws_size,
                              hipStream_t stream) {
    const float* x      = (const float*)d_in[0];
    const float* offset = (const float*)d_in[1];
    const float* mask   = (const float*)d_in[2];
    const float* weight = (const float*)d_in[3];
    float* out = (float*)d_out;

    const size_t wt_bytes = (size_t)K2_ * CIN * COUT * sizeof(float);
    if (ws_size >= wt_bytes) {
        float* wt = (float*)d_ws;
        DeformConv2d_wtrans<<<(COUT * CIN * K2_ + 255) / 256, 256, 0, stream>>>(weight, wt);
        DeformConv2d_kernel<true><<<1024, 256, 0, stream>>>(x, offset, mask, weight, wt, out);
    } else {
        DeformConv2d_kernel<false><<<1024, 256, 0, stream>>>(x, offset, mask, weight, nullptr, out);
    }
}